// Round 10
// baseline (373.210 us; speedup 1.0000x reference)
//
#include <hip/hip_runtime.h>
#include <hip/hip_cooperative_groups.h>

namespace cg = cooperative_groups;

// MaskedQueryAndGroup — masked ordered ball query + grouping.
// Shapes: B=4, NPOINT=2048, N=8192, C=64, NSAMPLE=32, R=0.1.
//
// Evidence log:
//  R1-R3: fp32 dataset; masks readable as int32; out = new_features
//    (B,67,NPOINT,32) ++ idx_mask (B,NPOINT,32), both f32.
//  R4 PASSED absmax 0.0: dot = fma(qz,z,fma(qy,y,qx*x)), ss/qq plain mul+add,
//    d2=(qq+ss)-2*dot, contract off; xyz epilogue (s-q)/0.1f. DO NOT CHANGE.
//  R5 FAILED: shfl_up+binary-search load balancer. Avoid exotic enumeration.
//  R6 PASSED: grid + x-run enumeration + 64-lane bitonic sort verified.
//  R7 129.1 / R8 122.4 / R9 124.2: harness poison fill ~58 us is fixed;
//    controllable ~66 us is dominated by 4 dependent dispatch floors
//    (gaps + ramp/tail), not instruction work (R9 ablation was neutral).
//  R10: ONE cooperative dispatch, grid.sync() between phases. 512 blocks x
//    1024 thr (one wave per query in phase 4; 2 blocks/CU: 36.9KB LDS,
//    launch_bounds(1024,8) caps VGPR 64). Verified scan/sort/gather logic
//    byte-preserved. Fallback to proven R9 4-dispatch path if coop enqueue
//    fails.

#define NPOINT 2048
#define NSUP   8192
#define NCH    64
#define NS     32
#define GRID1  10
#define CELLS  1000   // 10*10*10
#define QCHUNK 1024   // queries per gather tile

// ---------- helpers ----------
__device__ __forceinline__ bool probe_mask4(const void* mask) {
    // int32/f32 masks have byte 4i+1 == 0 always; byte bools ~90% nonzero.
    const unsigned char* mb = (const unsigned char*)mask;
    const int lane = threadIdx.x & 63;
    return __ballot(mb[4 * lane + 1] != 0) == 0ull;
}
__device__ __forceinline__ bool read_mask(const void* mask, int i, bool is4) {
    return is4 ? (((const int*)mask)[i] != 0)
               : (((const unsigned char*)mask)[i] != 0);
}
__device__ __forceinline__ int cell_of(float x, float y, float z) {
    const int cx = min(GRID1 - 1, (int)(x * 10.0f));
    const int cy = min(GRID1 - 1, (int)(y * 10.0f));
    const int cz = min(GRID1 - 1, (int)(z * 10.0f));
    return cx + GRID1 * cy + GRID1 * GRID1 * cz;
}

// ================= MEGA KERNEL (cooperative, 512 x 1024) ==================
__global__ __launch_bounds__(1024, 8) void mqag_mega(
    const float* __restrict__ query_xyz, const float* __restrict__ support_xyz,
    const void* __restrict__ query_mask, const void* __restrict__ support_mask,
    const float* __restrict__ features,
    float4* __restrict__ pts, int* __restrict__ starts,
    int* __restrict__ cursors, int* __restrict__ idx_ws,
    float* __restrict__ out, int B)
{
#pragma clang fp contract(off)
    __shared__ __align__(16) char smem[36992];   // union: row+qrow / scan / hits
    cg::grid_group gg = cg::this_grid();
    const int tid   = threadIdx.x;
    const int gsize = gridDim.x * 1024;
    const int gtid  = blockIdx.x * 1024 + tid;

    // ---- phase 0: zero starts + cursors (contiguous in ws) ----
    {
        const int nz = B * (CELLS + 1) + B * CELLS;
        for (int i = gtid; i < nz; i += gsize) starts[i] = 0;
    }
    gg.sync();

    // ---- phase 1: histogram ----
    {
        const bool m4 = probe_mask4(support_mask);
        for (int g = gtid; g < B * NSUP; g += gsize) {
            const int b = g / NSUP, n = g % NSUP;
            if (read_mask(support_mask, g, m4)) {
                const float* sx = support_xyz + (size_t)b * 3 * NSUP;
                const int cid = cell_of(sx[n], sx[NSUP + n], sx[2 * NSUP + n]);
                atomicAdd(&starts[b * (CELLS + 1) + cid + 1], 1);
            }
        }
    }
    gg.sync();

    // ---- phase 2: scan (R6-verified Hillis-Steele; first B blocks) ----
    if ((int)blockIdx.x < B) {
        int* scanb = (int*)smem;
        int* sb = starts + blockIdx.x * (CELLS + 1);
        scanb[tid] = (tid < CELLS) ? sb[tid + 1] : 0;
        __syncthreads();
        for (int d = 1; d < 1024; d <<= 1) {
            int v = 0;
            if (tid >= d) v = scanb[tid - d];
            __syncthreads();
            if (tid >= d) scanb[tid] += v;
            __syncthreads();
        }
        if (tid < CELLS) sb[tid + 1] = scanb[tid];   // sb[0] zeroed phase 0
    }
    gg.sync();

    // ---- phase 3: fill pts ----
    {
        const bool m4 = probe_mask4(support_mask);
        for (int g = gtid; g < B * NSUP; g += gsize) {
            const int b = g / NSUP, n = g % NSUP;
            if (read_mask(support_mask, g, m4)) {
                const float* sx = support_xyz + (size_t)b * 3 * NSUP;
                const float x = sx[n], y = sx[NSUP + n], z = sx[2 * NSUP + n];
                const int cid = cell_of(x, y, z);
                const int pos = starts[b * (CELLS + 1) + cid]
                              + atomicAdd(&cursors[b * CELLS + cid], 1);
                pts[(size_t)b * NSUP + pos] =
                    make_float4(x, y, z, __int_as_float(n));
            }
        }
    }
    gg.sync();

    // ---- phase 4: query — exactly one wave per query ----
    {
        const int wib  = tid >> 6;            // 0..15
        const int lane = tid & 63;
        int* hits  = (int*)smem + wib * 96;
        int* slots = hits + 64;
        const int qid = blockIdx.x * 16 + wib;   // grid = B*NPOINT/16
        const int b   = qid / NPOINT;
        const int p   = qid % NPOINT;

        const bool m4s = probe_mask4(support_mask);
        const bool m4q = probe_mask4(query_mask);

        const float* sx = support_xyz + (size_t)b * 3 * NSUP;
        const float* sy = sx + NSUP;
        const float* sz = sx + 2 * NSUP;

        const float qx = query_xyz[(size_t)b * 3 * NPOINT + p];
        const float qy = query_xyz[(size_t)b * 3 * NPOINT + NPOINT + p];
        const float qz = query_xyz[(size_t)b * 3 * NPOINT + 2 * NPOINT + p];
        const bool  qm = read_mask(query_mask, b * NPOINT + p, m4q);
        const float qq = (qx * qx + qy * qy) + qz * qz;  // no fma (ref)

        int cnt = 0;
        if (qm) {
            const int x0 = max(0, (int)floorf((qx - 0.101f) * 10.f));
            const int x1 = min(GRID1 - 1, (int)floorf((qx + 0.101f) * 10.f));
            const int y0 = max(0, (int)floorf((qy - 0.101f) * 10.f));
            const int y1 = min(GRID1 - 1, (int)floorf((qy + 0.101f) * 10.f));
            const int z0 = max(0, (int)floorf((qz - 0.101f) * 10.f));
            const int z1 = min(GRID1 - 1, (int)floorf((qz + 0.101f) * 10.f));
            const int ncx = x1 - x0 + 1;

            const int*    stb  = starts + b * (CELLS + 1);
            const float4* ptsb = pts + (size_t)b * NSUP;

            // x-consecutive cells -> contiguous pts range (R6-verified).
            for (int cz = z0; cz <= z1; ++cz) {
                for (int cy = y0; cy <= y1; ++cy) {
                    const int c0 = x0 + GRID1 * cy + GRID1 * GRID1 * cz;
                    const int s0 = stb[c0];
                    const int e0 = stb[c0 + ncx];
                    for (int tb = s0; tb < e0; tb += 64) {
                        const int g  = tb + lane;
                        const bool valid = g < e0;
                        const float4 pv = ptsb[valid ? g : (e0 - 1)];
                        const int nidx = __float_as_int(pv.w);
                        // EXACT R4 membership arithmetic:
                        const float ss  = (pv.x * pv.x + pv.y * pv.y) + pv.z * pv.z;
                        const float dot = __builtin_fmaf(qz, pv.z,
                                          __builtin_fmaf(qy, pv.y, qx * pv.x));
                        const float d2  = (qq + ss) - 2.0f * dot;
                        const bool within = valid && (d2 <= 0.01f);
                        const unsigned long long bal = __ballot(within);
                        if (within) {
                            const int r = cnt + __popcll(bal & ((1ull << lane) - 1ull));
                            if (r < 64) hits[r] = nidx;
                        }
                        cnt += __popcll(bal);
                    }
                }
            }
        }

        __syncthreads();

        if (cnt > 64) {
            // rare overflow: exact ordered linear rescan (R4-verified loop)
            int c2 = 0;
            for (int basei = 0; basei < NSUP; basei += 64) {
                const int n = basei + lane;
                const float x = sx[n], y = sy[n], z = sz[n];
                const bool  m = read_mask(support_mask, b * NSUP + n, m4s);
                const float ss  = (x * x + y * y) + z * z;
                const float dot = __builtin_fmaf(qz, z,
                                  __builtin_fmaf(qy, y, qx * x));
                const float d2  = (qq + ss) - 2.0f * dot;
                const bool within = (d2 <= 0.01f) && m;
                const unsigned long long bal = __ballot(within);
                if (within) {
                    const int r = c2 + __popcll(bal & ((1ull << lane) - 1ull));
                    if (r < NS) slots[r] = n;
                }
                c2 += __popcll(bal);
                if (c2 >= NS) break;
            }
            cnt = c2;
        } else {
            // bitonic sort, 64 lanes ascending (R6-verified)
            int v = (lane < cnt) ? hits[lane] : 0x7FFFFFFF;
            #pragma unroll
            for (int k = 2; k <= 64; k <<= 1) {
                #pragma unroll
                for (int j = k >> 1; j > 0; j >>= 1) {
                    const int pv = __shfl_xor(v, j, 64);
                    const bool keep_min = ((lane & j) == 0) == ((lane & k) == 0);
                    const int mn = min(v, pv), mx = max(v, pv);
                    v = keep_min ? mn : mx;
                }
            }
            if (lane < NS && lane < cnt) slots[lane] = v;
        }
        const int found = (cnt < NS) ? cnt : NS;

        __syncthreads();
        const int first = (found > 0) ? slots[0] : 0;
        if (lane < NS && lane >= found) slots[lane] = first;
        __syncthreads();

        if (lane < NS) idx_ws[((size_t)b * NPOINT + p) * NS + lane] = slots[lane];

        const size_t nf_elems = (size_t)B * 67 * NPOINT * NS;
        if (lane < NS) {
            out[nf_elems + ((size_t)b * NPOINT + p) * NS + lane] =
                (lane < found) ? 1.0f : 0.0f;
        }
    }
    gg.sync();

    // ---- phase 5: gather all 67 channels (R9-verified tile logic) ----
    {
        float* row  = (float*)smem;                   // 32 KB
        float* qrow = (float*)smem + NSUP;            // 4 KB
        const int ntiles = B * 67 * (NPOINT / QCHUNK);   // 536
        for (int tile = blockIdx.x; tile < ntiles; tile += gridDim.x) {
            const int t2 = tile >> 1;                 // NPOINT/QCHUNK == 2
            const int px = tile & 1;
            const int b  = t2 / 67, c = t2 % 67;
            const int p0 = px * QCHUNK;
            const bool is_xyz = (c < 3);

            __syncthreads();   // prior tile's row reads complete
            const float* src = is_xyz
                ? support_xyz + ((size_t)b * 3 + c) * NSUP
                : features + ((size_t)b * NCH + (c - 3)) * NSUP;
            const float4* src4 = (const float4*)src;
            for (int i = tid; i < NSUP / 4; i += 1024)
                ((float4*)row)[i] = src4[i];
            if (is_xyz) {
                const float* qsrc = query_xyz + ((size_t)b * 3 + c) * NPOINT + p0;
                for (int i = tid; i < QCHUNK; i += 1024) qrow[i] = qsrc[i];
            }
            __syncthreads();

            const int4* idx4 = (const int4*)(idx_ws + ((size_t)b * NPOINT + p0) * NS);
            float4* dst4 = (float4*)(out + (((size_t)b * 67 + c) * NPOINT + p0) * NS);
            if (is_xyz) {
                for (int e = tid; e < QCHUNK * NS / 4; e += 1024) {
                    const int4 iv = idx4[e];
                    const float q = qrow[e >> 3];
                    // EXACT R4 epilogue ops: (s - q) / 0.1f in fp32
                    dst4[e] = make_float4((row[iv.x] - q) / 0.1f,
                                          (row[iv.y] - q) / 0.1f,
                                          (row[iv.z] - q) / 0.1f,
                                          (row[iv.w] - q) / 0.1f);
                }
            } else {
                for (int e = tid; e < QCHUNK * NS / 4; e += 1024) {
                    const int4 iv = idx4[e];
                    dst4[e] = make_float4(row[iv.x], row[iv.y], row[iv.z], row[iv.w]);
                }
            }
        }
    }
}

// ================= R9 fallback kernels (proven, 4 dispatches) =============
__global__ __launch_bounds__(1024) void grid_hist_scan(
    const float* __restrict__ support_xyz, const void* __restrict__ support_mask,
    int* __restrict__ starts, int* __restrict__ cursors)
{
    __shared__ int cnt_s[CELLS];
    __shared__ int scanb[1024];
    const int tid = threadIdx.x;
    const int b   = blockIdx.x;
    const bool m4 = probe_mask4(support_mask);

    const float* sx = support_xyz + (size_t)b * 3 * NSUP;
    for (int i = tid; i < CELLS; i += 1024) cnt_s[i] = 0;
    __syncthreads();
    for (int n = tid; n < NSUP; n += 1024) {
        if (read_mask(support_mask, b * NSUP + n, m4)) {
            const int cid = cell_of(sx[n], sx[NSUP + n], sx[2 * NSUP + n]);
            atomicAdd(&cnt_s[cid], 1);
        }
    }
    __syncthreads();
    scanb[tid] = (tid < CELLS) ? cnt_s[tid] : 0;
    __syncthreads();
    for (int d = 1; d < 1024; d <<= 1) {
        int v = 0;
        if (tid >= d) v = scanb[tid - d];
        __syncthreads();
        if (tid >= d) scanb[tid] += v;
        __syncthreads();
    }
    int* sb = starts + b * (CELLS + 1);
    if (tid == 0) sb[0] = 0;
    if (tid < CELLS) sb[tid + 1] = scanb[tid];
    for (int i = tid; i < CELLS; i += 1024) cursors[b * CELLS + i] = 0;
}

__global__ __launch_bounds__(256) void grid_fill(
    const float* __restrict__ support_xyz, const void* __restrict__ support_mask,
    const int* __restrict__ starts, int* __restrict__ cursors,
    float4* __restrict__ pts)
{
    const bool m4 = probe_mask4(support_mask);
    const int gid = blockIdx.x * 256 + threadIdx.x;
    const int b = gid / NSUP, n = gid % NSUP;
    if (!read_mask(support_mask, gid, m4)) return;
    const float* sx = support_xyz + (size_t)b * 3 * NSUP;
    const float x = sx[n], y = sx[NSUP + n], z = sx[2 * NSUP + n];
    const int cid = cell_of(x, y, z);
    const int pos = starts[b * (CELLS + 1) + cid]
                  + atomicAdd(&cursors[b * CELLS + cid], 1);
    pts[(size_t)b * NSUP + pos] = make_float4(x, y, z, __int_as_float(n));
}

__global__ __launch_bounds__(256) void mqag_query(
    const float* __restrict__ query_xyz, const float* __restrict__ support_xyz,
    const void* __restrict__ query_mask, const void* __restrict__ support_mask,
    const float4* __restrict__ pts, const int* __restrict__ starts,
    int* __restrict__ idx_ws, float* __restrict__ out, int B)
{
#pragma clang fp contract(off)
    const int wib  = threadIdx.x >> 6;
    const int lane = threadIdx.x & 63;
    const int qid  = blockIdx.x * 4 + wib;
    const int b    = qid / NPOINT;
    const int p    = qid % NPOINT;

    __shared__ int hits_all[4][64];
    __shared__ int slots_all[4][NS];
    int* hits  = hits_all[wib];
    int* slots = slots_all[wib];

    const bool m4s = probe_mask4(support_mask);
    const bool m4q = probe_mask4(query_mask);

    const float* sx = support_xyz + (size_t)b * 3 * NSUP;
    const float* sy = sx + NSUP;
    const float* sz = sx + 2 * NSUP;

    const float qx = query_xyz[(size_t)b * 3 * NPOINT + p];
    const float qy = query_xyz[(size_t)b * 3 * NPOINT + NPOINT + p];
    const float qz = query_xyz[(size_t)b * 3 * NPOINT + 2 * NPOINT + p];
    const bool  qm = read_mask(query_mask, b * NPOINT + p, m4q);
    const float qq = (qx * qx + qy * qy) + qz * qz;

    int cnt = 0;
    if (qm) {
        const int x0 = max(0, (int)floorf((qx - 0.101f) * 10.f));
        const int x1 = min(GRID1 - 1, (int)floorf((qx + 0.101f) * 10.f));
        const int y0 = max(0, (int)floorf((qy - 0.101f) * 10.f));
        const int y1 = min(GRID1 - 1, (int)floorf((qy + 0.101f) * 10.f));
        const int z0 = max(0, (int)floorf((qz - 0.101f) * 10.f));
        const int z1 = min(GRID1 - 1, (int)floorf((qz + 0.101f) * 10.f));
        const int ncx = x1 - x0 + 1;
        const int*    stb  = starts + b * (CELLS + 1);
        const float4* ptsb = pts + (size_t)b * NSUP;
        for (int cz = z0; cz <= z1; ++cz) {
            for (int cy = y0; cy <= y1; ++cy) {
                const int c0 = x0 + GRID1 * cy + GRID1 * GRID1 * cz;
                const int s0 = stb[c0];
                const int e0 = stb[c0 + ncx];
                for (int tb = s0; tb < e0; tb += 64) {
                    const int g  = tb + lane;
                    const bool valid = g < e0;
                    const float4 pv = ptsb[valid ? g : (e0 - 1)];
                    const int nidx = __float_as_int(pv.w);
                    const float ss  = (pv.x * pv.x + pv.y * pv.y) + pv.z * pv.z;
                    const float dot = __builtin_fmaf(qz, pv.z,
                                      __builtin_fmaf(qy, pv.y, qx * pv.x));
                    const float d2  = (qq + ss) - 2.0f * dot;
                    const bool within = valid && (d2 <= 0.01f);
                    const unsigned long long bal = __ballot(within);
                    if (within) {
                        const int r = cnt + __popcll(bal & ((1ull << lane) - 1ull));
                        if (r < 64) hits[r] = nidx;
                    }
                    cnt += __popcll(bal);
                }
            }
        }
    }
    __syncthreads();
    if (cnt > 64) {
        int c2 = 0;
        for (int basei = 0; basei < NSUP; basei += 64) {
            const int n = basei + lane;
            const float x = sx[n], y = sy[n], z = sz[n];
            const bool  m = read_mask(support_mask, b * NSUP + n, m4s);
            const float ss  = (x * x + y * y) + z * z;
            const float dot = __builtin_fmaf(qz, z, __builtin_fmaf(qy, y, qx * x));
            const float d2  = (qq + ss) - 2.0f * dot;
            const bool within = (d2 <= 0.01f) && m;
            const unsigned long long bal = __ballot(within);
            if (within) {
                const int r = c2 + __popcll(bal & ((1ull << lane) - 1ull));
                if (r < NS) slots[r] = n;
            }
            c2 += __popcll(bal);
            if (c2 >= NS) break;
        }
        cnt = c2;
    } else {
        int v = (lane < cnt) ? hits[lane] : 0x7FFFFFFF;
        #pragma unroll
        for (int k = 2; k <= 64; k <<= 1) {
            #pragma unroll
            for (int j = k >> 1; j > 0; j >>= 1) {
                const int pv = __shfl_xor(v, j, 64);
                const bool keep_min = ((lane & j) == 0) == ((lane & k) == 0);
                const int mn = min(v, pv), mx = max(v, pv);
                v = keep_min ? mn : mx;
            }
        }
        if (lane < NS && lane < cnt) slots[lane] = v;
    }
    const int found = (cnt < NS) ? cnt : NS;
    __syncthreads();
    const int first = (found > 0) ? slots[0] : 0;
    if (lane < NS && lane >= found) slots[lane] = first;
    __syncthreads();
    if (lane < NS) idx_ws[((size_t)b * NPOINT + p) * NS + lane] = slots[lane];
    const size_t nf_elems = (size_t)B * 67 * NPOINT * NS;
    if (lane < NS) {
        out[nf_elems + ((size_t)b * NPOINT + p) * NS + lane] =
            (lane < found) ? 1.0f : 0.0f;
    }
}

__global__ __launch_bounds__(256) void gather_all(
    const float* __restrict__ support_xyz, const float* __restrict__ query_xyz,
    const float* __restrict__ features, const int* __restrict__ idx_ws,
    float* __restrict__ out, int B)
{
    __shared__ float row[NSUP];
    __shared__ float qrow[QCHUNK];
    const int bc = blockIdx.y;
    const int b  = bc / 67, c = bc % 67;
    const int p0 = blockIdx.x * QCHUNK;
    const bool is_xyz = (c < 3);

    const float* src = is_xyz
        ? support_xyz + ((size_t)b * 3 + c) * NSUP
        : features + ((size_t)b * NCH + (c - 3)) * NSUP;
    const float4* src4 = (const float4*)src;
    for (int i = threadIdx.x; i < NSUP / 4; i += 256)
        ((float4*)row)[i] = src4[i];
    if (is_xyz) {
        const float* qsrc = query_xyz + ((size_t)b * 3 + c) * NPOINT + p0;
        for (int i = threadIdx.x; i < QCHUNK; i += 256) qrow[i] = qsrc[i];
    }
    __syncthreads();

    const int4* idx4 = (const int4*)(idx_ws + ((size_t)b * NPOINT + p0) * NS);
    float4* dst4 = (float4*)(out + (((size_t)b * 67 + c) * NPOINT + p0) * NS);
    if (is_xyz) {
        for (int e = threadIdx.x; e < QCHUNK * NS / 4; e += 256) {
            const int4 iv = idx4[e];
            const float q = qrow[e >> 3];
            dst4[e] = make_float4((row[iv.x] - q) / 0.1f,
                                  (row[iv.y] - q) / 0.1f,
                                  (row[iv.z] - q) / 0.1f,
                                  (row[iv.w] - q) / 0.1f);
        }
    } else {
        for (int e = threadIdx.x; e < QCHUNK * NS / 4; e += 256) {
            const int4 iv = idx4[e];
            dst4[e] = make_float4(row[iv.x], row[iv.y], row[iv.z], row[iv.w]);
        }
    }
}

extern "C" void kernel_launch(void* const* d_in, const int* in_sizes, int n_in,
                              void* d_out, int out_size, void* d_ws, size_t ws_size,
                              hipStream_t stream) {
    const float* query_xyz    = (const float*)d_in[0];
    const float* support_xyz  = (const float*)d_in[1];
    const void*  query_mask   = d_in[2];
    const void*  support_mask = d_in[3];
    const float* features     = (const float*)d_in[4];

    const int B = in_sizes[0] / (3 * NPOINT);      // = 4

    // ws layout: pts | starts | cursors | idx (starts+cursors contiguous)
    const size_t off_pts     = 0;
    const size_t off_starts  = off_pts + (size_t)B * NSUP * sizeof(float4);
    const size_t off_cursors = off_starts + (size_t)B * (CELLS + 1) * sizeof(int);
    const size_t off_idx     = off_cursors + (size_t)B * CELLS * sizeof(int);
    const size_t need = off_idx + (size_t)B * NPOINT * NS * sizeof(int);
    if (ws_size < need) return;   // shapes are fixed; ws is ample in practice

    float4* pts  = (float4*)((char*)d_ws + off_pts);
    int* starts  = (int*)((char*)d_ws + off_starts);
    int* cursors = (int*)((char*)d_ws + off_cursors);
    int* idx_ws  = (int*)((char*)d_ws + off_idx);
    float* outp  = (float*)d_out;

    // One cooperative dispatch: 512 blocks x 1024 thr (one wave per query).
    int Bv = B;
    void* args[] = { (void*)&query_xyz, (void*)&support_xyz, (void*)&query_mask,
                     (void*)&support_mask, (void*)&features, (void*)&pts,
                     (void*)&starts, (void*)&cursors, (void*)&idx_ws,
                     (void*)&outp, (void*)&Bv };
    const dim3 cgrid(B * NPOINT / 16);   // 16 waves/block, 1 query/wave
    const dim3 cblock(1024);
    hipError_t err = hipLaunchCooperativeKernel((void*)mqag_mega, cgrid, cblock,
                                                args, 0, stream);
    if (err == hipSuccess) return;
    (void)hipGetLastError();             // clear; fall back to R9 path

    hipLaunchKernelGGL(grid_hist_scan, dim3(B), dim3(1024), 0, stream,
                       support_xyz, support_mask, starts, cursors);
    hipLaunchKernelGGL(grid_fill, dim3(B * NSUP / 256), dim3(256), 0,
                       stream, support_xyz, support_mask, starts, cursors, pts);
    hipLaunchKernelGGL(mqag_query, dim3(B * NPOINT / 4), dim3(256), 0,
                       stream, query_xyz, support_xyz, query_mask,
                       support_mask, pts, starts, idx_ws, outp, B);
    hipLaunchKernelGGL(gather_all, dim3(NPOINT / QCHUNK, B * 67), dim3(256),
                       0, stream, support_xyz, query_xyz, features, idx_ws,
                       outp, B);
}

// Round 11
// 137.144 us; speedup vs baseline: 2.7213x; 2.7213x over previous
//
#include <hip/hip_runtime.h>

// MaskedQueryAndGroup — masked ordered ball query + grouping.
// Shapes: B=4, NPOINT=2048, N=8192, C=64, NSAMPLE=32, R=0.1.
//
// Evidence log:
//  R1-R3: fp32 dataset; masks readable as int32; out = new_features
//    (B,67,NPOINT,32) ++ idx_mask (B,NPOINT,32), both f32.
//  R4 PASSED absmax 0.0: dot = fma(qz,z,fma(qy,y,qx*x)), ss/qq plain mul+add,
//    d2=(qq+ss)-2*dot, contract off; xyz epilogue (s-q)/0.1f. DO NOT CHANGE.
//  R5 FAILED: shfl_up+binary-search load balancer. Avoid exotic enumeration.
//  R6 PASSED: grid + x-run enumeration + 64-lane bitonic sort verified.
//  R7 129.1 / R8 122.4 / R9 124.2: harness poison fill ~58 us fixed floor;
//    controllable ~64 us = query ~20 + gather ~18 + build ~15 + gaps.
//  R10 FAILED PERF (285 us in-kernel): cooperative grid.sync() ~45 us EACH
//    on MI355X (8 non-coherent XCDs, device-scope spin). NEVER fuse short
//    phases with grid sync here; kernel boundary ~2 us is cheaper.
//  R11: revert to R9 structure; coarsen grid to 10x5x5 (cell 0.1x0.2x0.2).
//    Query loop: ~4-6 x-run ranges x ~75 candidates (full-width chunks)
//    instead of 9-16 thin ranges -> serialized chunk iterations ~16 -> ~7.
//    All membership/sort/gather logic byte-identical to verified code.

#define NPOINT 2048
#define NSUP   8192
#define NCH    64
#define NS     32
#define GX     10
#define GY     5
#define GZ     5
#define CELLS  (GX * GY * GZ)   // 250
#define QCHUNK 1024             // queries per gather block

// ---------- helpers ----------
__device__ __forceinline__ bool probe_mask4(const void* mask) {
    // int32/f32 masks have byte 4i+1 == 0 always; byte bools ~90% nonzero.
    const unsigned char* mb = (const unsigned char*)mask;
    const int lane = threadIdx.x & 63;
    return __ballot(mb[4 * lane + 1] != 0) == 0ull;
}
__device__ __forceinline__ bool read_mask(const void* mask, int i, bool is4) {
    return is4 ? (((const int*)mask)[i] != 0)
               : (((const unsigned char*)mask)[i] != 0);
}
__device__ __forceinline__ int cell_of(float x, float y, float z) {
    const int cx = min(GX - 1, (int)(x * 10.0f));
    const int cy = min(GY - 1, (int)(y * 5.0f));
    const int cz = min(GZ - 1, (int)(z * 5.0f));
    return cx + GX * cy + GX * GY * cz;
}

// ---------- build A: histogram + scan + cursor zero (1 block per batch) ----
__global__ __launch_bounds__(256) void grid_hist_scan(
    const float* __restrict__ support_xyz, const void* __restrict__ support_mask,
    int* __restrict__ starts, int* __restrict__ cursors)
{
    __shared__ int cnt_s[CELLS];
    __shared__ int scanb[256];
    const int tid = threadIdx.x;
    const int b   = blockIdx.x;
    const bool m4 = probe_mask4(support_mask);

    const float* sx = support_xyz + (size_t)b * 3 * NSUP;
    for (int i = tid; i < CELLS; i += 256) cnt_s[i] = 0;
    __syncthreads();

    for (int n = tid; n < NSUP; n += 256) {
        if (read_mask(support_mask, b * NSUP + n, m4)) {
            const int cid = cell_of(sx[n], sx[NSUP + n], sx[2 * NSUP + n]);
            atomicAdd(&cnt_s[cid], 1);
        }
    }
    __syncthreads();

    // Hillis-Steele inclusive scan (verified pattern, 256-wide, CELLS<=256)
    scanb[tid] = (tid < CELLS) ? cnt_s[tid] : 0;
    __syncthreads();
    for (int d = 1; d < 256; d <<= 1) {
        int v = 0;
        if (tid >= d) v = scanb[tid - d];
        __syncthreads();
        if (tid >= d) scanb[tid] += v;
        __syncthreads();
    }
    int* sb = starts + b * (CELLS + 1);
    if (tid == 0) sb[0] = 0;
    if (tid < CELLS) sb[tid + 1] = scanb[tid];
    for (int i = tid; i < CELLS; i += 256) cursors[b * CELLS + i] = 0;
}

// ---------- build B: fill pts (R8/R9-verified) ----------
__global__ __launch_bounds__(256) void grid_fill(
    const float* __restrict__ support_xyz, const void* __restrict__ support_mask,
    const int* __restrict__ starts, int* __restrict__ cursors,
    float4* __restrict__ pts)
{
    const bool m4 = probe_mask4(support_mask);
    const int gid = blockIdx.x * 256 + threadIdx.x;
    const int b = gid / NSUP, n = gid % NSUP;
    if (!read_mask(support_mask, gid, m4)) return;
    const float* sx = support_xyz + (size_t)b * 3 * NSUP;
    const float x = sx[n], y = sx[NSUP + n], z = sx[2 * NSUP + n];
    const int cid = cell_of(x, y, z);
    const int pos = starts[b * (CELLS + 1) + cid]
                  + atomicAdd(&cursors[b * CELLS + cid], 1);
    pts[(size_t)b * NSUP + pos] = make_float4(x, y, z, __int_as_float(n));
}

// ---------- query: scan + sort -> idx_ws + idx_mask (4 queries/block) ------
__global__ __launch_bounds__(256) void mqag_query(
    const float* __restrict__ query_xyz, const float* __restrict__ support_xyz,
    const void* __restrict__ query_mask, const void* __restrict__ support_mask,
    const float4* __restrict__ pts, const int* __restrict__ starts,
    int* __restrict__ idx_ws, float* __restrict__ out, int B)
{
#pragma clang fp contract(off)
    const int wib  = threadIdx.x >> 6;
    const int lane = threadIdx.x & 63;
    const int qid  = blockIdx.x * 4 + wib;
    const int b    = qid / NPOINT;
    const int p    = qid % NPOINT;

    __shared__ int hits_all[4][64];
    __shared__ int slots_all[4][NS];
    int* hits  = hits_all[wib];
    int* slots = slots_all[wib];

    const bool m4s = probe_mask4(support_mask);
    const bool m4q = probe_mask4(query_mask);

    const float* sx = support_xyz + (size_t)b * 3 * NSUP;
    const float* sy = sx + NSUP;
    const float* sz = sx + 2 * NSUP;

    const float qx = query_xyz[(size_t)b * 3 * NPOINT + p];
    const float qy = query_xyz[(size_t)b * 3 * NPOINT + NPOINT + p];
    const float qz = query_xyz[(size_t)b * 3 * NPOINT + 2 * NPOINT + p];
    const bool  qm = read_mask(query_mask, b * NPOINT + p, m4q);
    const float qq = (qx * qx + qy * qy) + qz * qz;   // no fma (matches ref)

    int cnt = 0;
    if (qm) {
        // cells overlapping the ball, margin 1e-3 >> fp slop (~1e-6)
        const int x0 = max(0, (int)floorf((qx - 0.101f) * 10.f));
        const int x1 = min(GX - 1, (int)floorf((qx + 0.101f) * 10.f));
        const int y0 = max(0, (int)floorf((qy - 0.101f) * 5.f));
        const int y1 = min(GY - 1, (int)floorf((qy + 0.101f) * 5.f));
        const int z0 = max(0, (int)floorf((qz - 0.101f) * 5.f));
        const int z1 = min(GZ - 1, (int)floorf((qz + 0.101f) * 5.f));
        const int ncx = x1 - x0 + 1;

        const int*    stb  = starts + b * (CELLS + 1);
        const float4* ptsb = pts + (size_t)b * NSUP;

        // x-consecutive cells -> contiguous pts range (R6-verified pattern).
        // pts is pre-filtered by support_mask (grid_fill) — no recheck.
        for (int cz = z0; cz <= z1; ++cz) {
            for (int cy = y0; cy <= y1; ++cy) {
                const int c0 = x0 + GX * cy + GX * GY * cz;
                const int s0 = stb[c0];
                const int e0 = stb[c0 + ncx];
                for (int tb = s0; tb < e0; tb += 64) {
                    const int g  = tb + lane;
                    const bool valid = g < e0;
                    const float4 pv = ptsb[valid ? g : (e0 - 1)];
                    const int nidx = __float_as_int(pv.w);
                    // EXACT R4 membership arithmetic (bit-exact vs ref):
                    const float ss  = (pv.x * pv.x + pv.y * pv.y) + pv.z * pv.z;
                    const float dot = __builtin_fmaf(qz, pv.z,
                                      __builtin_fmaf(qy, pv.y, qx * pv.x));
                    const float d2  = (qq + ss) - 2.0f * dot;
                    const bool within = valid && (d2 <= 0.01f);
                    const unsigned long long bal = __ballot(within);
                    if (within) {
                        const int r = cnt + __popcll(bal & ((1ull << lane) - 1ull));
                        if (r < 64) hits[r] = nidx;
                    }
                    cnt += __popcll(bal);
                }
            }
        }
    }

    __syncthreads();

    if (cnt > 64) {
        // rare overflow: exact ordered linear rescan (R4-verified loop)
        int c2 = 0;
        for (int basei = 0; basei < NSUP; basei += 64) {
            const int n = basei + lane;
            const float x = sx[n], y = sy[n], z = sz[n];
            const bool  m = read_mask(support_mask, b * NSUP + n, m4s);
            const float ss  = (x * x + y * y) + z * z;
            const float dot = __builtin_fmaf(qz, z,
                              __builtin_fmaf(qy, y, qx * x));
            const float d2  = (qq + ss) - 2.0f * dot;
            const bool within = (d2 <= 0.01f) && m;
            const unsigned long long bal = __ballot(within);
            if (within) {
                const int r = c2 + __popcll(bal & ((1ull << lane) - 1ull));
                if (r < NS) slots[r] = n;
            }
            c2 += __popcll(bal);
            if (c2 >= NS) break;
        }
        cnt = c2;
    } else {
        // bitonic sort, 64 lanes ascending (R6-verified); empties = INT_MAX
        int v = (lane < cnt) ? hits[lane] : 0x7FFFFFFF;
        #pragma unroll
        for (int k = 2; k <= 64; k <<= 1) {
            #pragma unroll
            for (int j = k >> 1; j > 0; j >>= 1) {
                const int pv = __shfl_xor(v, j, 64);
                const bool keep_min = ((lane & j) == 0) == ((lane & k) == 0);
                const int mn = min(v, pv), mx = max(v, pv);
                v = keep_min ? mn : mx;
            }
        }
        if (lane < NS && lane < cnt) slots[lane] = v;
    }
    const int found = (cnt < NS) ? cnt : NS;

    __syncthreads();
    const int first = (found > 0) ? slots[0] : 0;
    if (lane < NS && lane >= found) slots[lane] = first;
    __syncthreads();

    // padded idx -> ws (consumed by gather_all)
    if (lane < NS) idx_ws[((size_t)b * NPOINT + p) * NS + lane] = slots[lane];

    // idx_mask (f32 0/1) after new_features
    const size_t nf_elems = (size_t)B * 67 * NPOINT * NS;
    if (lane < NS) {
        out[nf_elems + ((size_t)b * NPOINT + p) * NS + lane] =
            (lane < found) ? 1.0f : 0.0f;
    }
}

// ---------- gather: all 67 channels; one row in LDS, coalesced in/out ------
__global__ __launch_bounds__(256) void gather_all(
    const float* __restrict__ support_xyz, const float* __restrict__ query_xyz,
    const float* __restrict__ features, const int* __restrict__ idx_ws,
    float* __restrict__ out, int B)
{
    __shared__ float row[NSUP];                       // 32 KB
    __shared__ float qrow[QCHUNK];                    // 4 KB
    const int bc = blockIdx.y;                        // b*67 + c_out
    const int b  = bc / 67, c = bc % 67;
    const int p0 = blockIdx.x * QCHUNK;
    const bool is_xyz = (c < 3);

    const float* src = is_xyz
        ? support_xyz + ((size_t)b * 3 + c) * NSUP
        : features + ((size_t)b * NCH + (c - 3)) * NSUP;
    const float4* src4 = (const float4*)src;
    for (int i = threadIdx.x; i < NSUP / 4; i += 256)
        ((float4*)row)[i] = src4[i];
    if (is_xyz) {
        const float* qsrc = query_xyz + ((size_t)b * 3 + c) * NPOINT + p0;
        for (int i = threadIdx.x; i < QCHUNK; i += 256) qrow[i] = qsrc[i];
    }
    __syncthreads();

    const int4* idx4 = (const int4*)(idx_ws + ((size_t)b * NPOINT + p0) * NS);
    float4* dst4 = (float4*)(out + (((size_t)b * 67 + c) * NPOINT + p0) * NS);
    if (is_xyz) {
        for (int e = threadIdx.x; e < QCHUNK * NS / 4; e += 256) {
            const int4 iv = idx4[e];
            const float q = qrow[e >> 3];             // 8 float4 per query
            // EXACT R4 epilogue ops: (s - q) / 0.1f in fp32
            dst4[e] = make_float4((row[iv.x] - q) / 0.1f,
                                  (row[iv.y] - q) / 0.1f,
                                  (row[iv.z] - q) / 0.1f,
                                  (row[iv.w] - q) / 0.1f);
        }
    } else {
        for (int e = threadIdx.x; e < QCHUNK * NS / 4; e += 256) {
            const int4 iv = idx4[e];
            dst4[e] = make_float4(row[iv.x], row[iv.y], row[iv.z], row[iv.w]);
        }
    }
}

// ---------- proven R4 linear kernel (fallback if ws tiny) ----------
__global__ __launch_bounds__(256) void mqag_linear(
    const float* __restrict__ query_xyz, const float* __restrict__ support_xyz,
    const void* __restrict__ query_mask_raw, const void* __restrict__ support_mask_raw,
    const float* __restrict__ features, float* __restrict__ out, int B)
{
#pragma clang fp contract(off)
    const int wib  = threadIdx.x >> 6;
    const int lane = threadIdx.x & 63;
    const int qid  = blockIdx.x * 4 + wib;
    const int b    = qid / NPOINT;
    const int p    = qid % NPOINT;

    __shared__ int slots_all[4][NS];
    int* slots = slots_all[wib];

    const bool m4s = probe_mask4(support_mask_raw);
    const bool m4q = probe_mask4(query_mask_raw);

    const float* sx = support_xyz + (size_t)b * 3 * NSUP;
    const float* sy = sx + NSUP;
    const float* sz = sx + 2 * NSUP;

    const float qx = query_xyz[(size_t)b * 3 * NPOINT + p];
    const float qy = query_xyz[(size_t)b * 3 * NPOINT + NPOINT + p];
    const float qz = query_xyz[(size_t)b * 3 * NPOINT + 2 * NPOINT + p];
    const bool  qm = read_mask(query_mask_raw, b * NPOINT + p, m4q);
    const float qq = (qx * qx + qy * qy) + qz * qz;

    int cnt = 0;
    if (qm) {
        for (int base = 0; base < NSUP; base += 64) {
            const int n = base + lane;
            const float x = sx[n], y = sy[n], z = sz[n];
            const bool  m = read_mask(support_mask_raw, b * NSUP + n, m4s);
            const float ss  = (x * x + y * y) + z * z;
            const float dot = __builtin_fmaf(qz, z, __builtin_fmaf(qy, y, qx * x));
            const float d2  = (qq + ss) - 2.0f * dot;
            const bool within = (d2 <= 0.01f) && m;
            const unsigned long long bal = __ballot(within);
            if (within) {
                const int r = cnt + __popcll(bal & ((1ull << lane) - 1ull));
                if (r < NS) slots[r] = n;
            }
            cnt += __popcll(bal);
            if (cnt >= NS) break;
        }
    }
    const int found = cnt < NS ? cnt : NS;
    __syncthreads();
    const int first = (found > 0) ? slots[0] : 0;
    if (lane < NS && lane >= found) slots[lane] = first;
    __syncthreads();

    const size_t nf_elems = (size_t)B * 67 * NPOINT * NS;
    if (lane < NS) {
        out[nf_elems + ((size_t)b * NPOINT + p) * NS + lane] =
            (lane < found) ? 1.0f : 0.0f;
    }
    const float* feat = features + (size_t)b * NCH * NSUP;
    for (int i = 0; i < (67 * NS + 63) / 64; ++i) {
        const int flat = i * 64 + lane;
        if (flat < 67 * NS) {
            const int ch = flat >> 5;
            const int k  = flat & 31;
            const int idx = slots[k];
            float val;
            if (ch < 3) {
                const float s = sx[(size_t)ch * NSUP + idx];
                const float q = (ch == 0) ? qx : ((ch == 1) ? qy : qz);
                val = (s - q) / 0.1f;
            } else {
                val = feat[(size_t)(ch - 3) * NSUP + idx];
            }
            out[(((size_t)b * 67 + ch) * NPOINT + p) * NS + k] = val;
        }
    }
}

extern "C" void kernel_launch(void* const* d_in, const int* in_sizes, int n_in,
                              void* d_out, int out_size, void* d_ws, size_t ws_size,
                              hipStream_t stream) {
    const float* query_xyz    = (const float*)d_in[0];
    const float* support_xyz  = (const float*)d_in[1];
    const void*  query_mask   = d_in[2];
    const void*  support_mask = d_in[3];
    const float* features     = (const float*)d_in[4];

    const int B = in_sizes[0] / (3 * NPOINT);      // = 4

    // ws layout: pts | starts | cursors | idx (starts+cursors contiguous)
    const size_t off_pts     = 0;
    const size_t off_starts  = off_pts + (size_t)B * NSUP * sizeof(float4);
    const size_t off_cursors = off_starts + (size_t)B * (CELLS + 1) * sizeof(int);
    const size_t off_idx     = off_cursors + (size_t)B * CELLS * sizeof(int);
    const size_t need = off_idx + (size_t)B * NPOINT * NS * sizeof(int);

    if (ws_size >= need) {
        float4* pts  = (float4*)((char*)d_ws + off_pts);
        int* starts  = (int*)((char*)d_ws + off_starts);
        int* cursors = (int*)((char*)d_ws + off_cursors);
        int* idx_ws  = (int*)((char*)d_ws + off_idx);

        hipLaunchKernelGGL(grid_hist_scan, dim3(B), dim3(256), 0, stream,
                           support_xyz, support_mask, starts, cursors);
        hipLaunchKernelGGL(grid_fill, dim3(B * NSUP / 256), dim3(256), 0,
                           stream, support_xyz, support_mask, starts, cursors, pts);
        hipLaunchKernelGGL(mqag_query, dim3(B * NPOINT / 4), dim3(256), 0,
                           stream, query_xyz, support_xyz, query_mask,
                           support_mask, pts, starts, idx_ws, (float*)d_out, B);
        hipLaunchKernelGGL(gather_all, dim3(NPOINT / QCHUNK, B * 67), dim3(256),
                           0, stream, support_xyz, query_xyz, features, idx_ws,
                           (float*)d_out, B);
    } else {
        hipLaunchKernelGGL(mqag_linear, dim3(B * NPOINT / 4), dim3(256), 0,
                           stream, query_xyz, support_xyz, query_mask,
                           support_mask, features, (float*)d_out, B);
    }
}

// Round 12
// 123.363 us; speedup vs baseline: 3.0253x; 1.1117x over previous
//
#include <hip/hip_runtime.h>

// MaskedQueryAndGroup — masked ordered ball query + grouping.
// Shapes: B=4, NPOINT=2048, N=8192, C=64, NSAMPLE=32, R=0.1.
//
// Evidence log:
//  R1-R3: fp32 dataset; masks readable as int32; out = new_features
//    (B,67,NPOINT,32) ++ idx_mask (B,NPOINT,32), both f32.
//  R4 PASSED absmax 0.0: dot = fma(qz,z,fma(qy,y,qx*x)), ss/qq plain mul+add,
//    d2=(qq+ss)-2*dot, contract off; xyz epilogue (s-q)/0.1f. DO NOT CHANGE.
//  R5 FAILED: shfl_up+binary-search load balancer. Avoid exotic enumeration.
//  R6 PASSED: 10x10x10 grid + x-run enumeration + bitonic sort verified.
//  R8 PASSED 122.4 — BEST. R9 (4-dispatch) 124.2 neutral.
//  R10 FAILED PERF: cooperative grid.sync() ~45 us each on MI355X. Never.
//  R11 REGRESSED 137.1: coarse 10x5x5 grid doubled candidates tested;
//    cell edge == R is the sweet spot.
//  R12: exact revert to R8 (empirical best). Fixed harness floor ~58 us
//    (poison fills, top-5 @ 78% HBM peak); controllable ~64 us has resisted
//    3 orthogonal structural attacks (R9/R10/R11).

#define NPOINT 2048
#define NSUP   8192
#define NCH    64
#define NS     32
#define GRID1  10
#define CELLS  1000   // 10*10*10
#define QCHUNK 1024   // queries per gather block

// ---------- helpers ----------
__device__ __forceinline__ bool probe_mask4(const void* mask) {
    // int32/f32 masks have byte 4i+1 == 0 always; byte bools ~90% nonzero.
    const unsigned char* mb = (const unsigned char*)mask;
    const int lane = threadIdx.x & 63;
    return __ballot(mb[4 * lane + 1] != 0) == 0ull;
}
__device__ __forceinline__ bool read_mask(const void* mask, int i, bool is4) {
    return is4 ? (((const int*)mask)[i] != 0)
               : (((const unsigned char*)mask)[i] != 0);
}
__device__ __forceinline__ int cell_of(float x, float y, float z) {
    const int cx = min(GRID1 - 1, (int)(x * 10.0f));
    const int cy = min(GRID1 - 1, (int)(y * 10.0f));
    const int cz = min(GRID1 - 1, (int)(z * 10.0f));
    return cx + GRID1 * cy + GRID1 * GRID1 * cz;
}

// ---------- build step 1: zero starts+cursors ----------
__global__ __launch_bounds__(256) void zero_ws(int* __restrict__ ptr, int n) {
    const int i = blockIdx.x * 256 + threadIdx.x;
    if (i < n) ptr[i] = 0;
}

// ---------- build step 2: histogram (counts at starts[b][cell+1]) ----------
__global__ __launch_bounds__(256) void grid_hist(
    const float* __restrict__ support_xyz, const void* __restrict__ support_mask,
    int* __restrict__ starts)
{
    const bool m4 = probe_mask4(support_mask);
    const int gid = blockIdx.x * 256 + threadIdx.x;   // grid sized B*NSUP exactly
    const int b = gid / NSUP, n = gid % NSUP;
    if (!read_mask(support_mask, gid, m4)) return;
    const float* sx = support_xyz + (size_t)b * 3 * NSUP;
    const int cid = cell_of(sx[n], sx[NSUP + n], sx[2 * NSUP + n]);
    atomicAdd(&starts[b * (CELLS + 1) + cid + 1], 1);
}

// ---------- build step 3: scan (R6-verified Hillis-Steele) ----------
__global__ __launch_bounds__(1024) void grid_scan(int* __restrict__ starts) {
    __shared__ int scanb[1024];
    const int tid = threadIdx.x;
    int* sb = starts + blockIdx.x * (CELLS + 1);
    scanb[tid] = (tid < CELLS) ? sb[tid + 1] : 0;
    __syncthreads();
    for (int d = 1; d < 1024; d <<= 1) {
        int v = 0;
        if (tid >= d) v = scanb[tid - d];
        __syncthreads();
        if (tid >= d) scanb[tid] += v;
        __syncthreads();
    }
    if (tid < CELLS) sb[tid + 1] = scanb[tid];   // sb[0] stays 0 (zero_ws)
}

// ---------- build step 4: fill pts ----------
__global__ __launch_bounds__(256) void grid_fill(
    const float* __restrict__ support_xyz, const void* __restrict__ support_mask,
    const int* __restrict__ starts, int* __restrict__ cursors,
    float4* __restrict__ pts)
{
    const bool m4 = probe_mask4(support_mask);
    const int gid = blockIdx.x * 256 + threadIdx.x;
    const int b = gid / NSUP, n = gid % NSUP;
    if (!read_mask(support_mask, gid, m4)) return;
    const float* sx = support_xyz + (size_t)b * 3 * NSUP;
    const float x = sx[n], y = sx[NSUP + n], z = sx[2 * NSUP + n];
    const int cid = cell_of(x, y, z);
    const int pos = starts[b * (CELLS + 1) + cid]
                  + atomicAdd(&cursors[b * CELLS + cid], 1);
    pts[(size_t)b * NSUP + pos] = make_float4(x, y, z, __int_as_float(n));
}

// ---------- query: scan + sort + idx/xyz/idx_mask (4 queries/block) ----------
__global__ __launch_bounds__(256) void mqag_query(
    const float* __restrict__ query_xyz, const float* __restrict__ support_xyz,
    const void* __restrict__ query_mask, const void* __restrict__ support_mask,
    const float4* __restrict__ pts, const int* __restrict__ starts,
    int* __restrict__ idx_ws, float* __restrict__ out, int B)
{
#pragma clang fp contract(off)
    const int wib  = threadIdx.x >> 6;
    const int lane = threadIdx.x & 63;
    const int qid  = blockIdx.x * 4 + wib;
    const int b    = qid / NPOINT;
    const int p    = qid % NPOINT;

    __shared__ int hits_all[4][64];
    __shared__ int slots_all[4][NS];
    int* hits  = hits_all[wib];
    int* slots = slots_all[wib];

    const bool m4s = probe_mask4(support_mask);
    const bool m4q = probe_mask4(query_mask);

    const float* sx = support_xyz + (size_t)b * 3 * NSUP;
    const float* sy = sx + NSUP;
    const float* sz = sx + 2 * NSUP;

    const float qx = query_xyz[(size_t)b * 3 * NPOINT + p];
    const float qy = query_xyz[(size_t)b * 3 * NPOINT + NPOINT + p];
    const float qz = query_xyz[(size_t)b * 3 * NPOINT + 2 * NPOINT + p];
    const bool  qm = read_mask(query_mask, b * NPOINT + p, m4q);
    const float qq = (qx * qx + qy * qy) + qz * qz;   // no fma (matches ref)

    int cnt = 0;
    if (qm) {
        const int x0 = max(0, (int)floorf((qx - 0.101f) * 10.f));
        const int x1 = min(GRID1 - 1, (int)floorf((qx + 0.101f) * 10.f));
        const int y0 = max(0, (int)floorf((qy - 0.101f) * 10.f));
        const int y1 = min(GRID1 - 1, (int)floorf((qy + 0.101f) * 10.f));
        const int z0 = max(0, (int)floorf((qz - 0.101f) * 10.f));
        const int z1 = min(GRID1 - 1, (int)floorf((qz + 0.101f) * 10.f));
        const int ncx = x1 - x0 + 1;

        const int*    stb  = starts + b * (CELLS + 1);
        const float4* ptsb = pts + (size_t)b * NSUP;

        // x-consecutive cells -> contiguous pts range (R6-verified).
        // pts is pre-filtered by support_mask (grid_fill).
        for (int cz = z0; cz <= z1; ++cz) {
            for (int cy = y0; cy <= y1; ++cy) {
                const int c0 = x0 + GRID1 * cy + GRID1 * GRID1 * cz;
                const int s0 = stb[c0];
                const int e0 = stb[c0 + ncx];
                for (int tb = s0; tb < e0; tb += 64) {
                    const int g  = tb + lane;
                    const bool valid = g < e0;
                    const float4 pv = ptsb[valid ? g : (e0 - 1)];
                    const int nidx = __float_as_int(pv.w);
                    // EXACT R4 membership arithmetic (bit-exact vs ref):
                    const float ss  = (pv.x * pv.x + pv.y * pv.y) + pv.z * pv.z;
                    const float dot = __builtin_fmaf(qz, pv.z,
                                      __builtin_fmaf(qy, pv.y, qx * pv.x));
                    const float d2  = (qq + ss) - 2.0f * dot;
                    const bool within = valid && (d2 <= 0.01f)
                        && read_mask(support_mask, b * NSUP + nidx, m4s);
                    const unsigned long long bal = __ballot(within);
                    if (within) {
                        const int r = cnt + __popcll(bal & ((1ull << lane) - 1ull));
                        if (r < 64) hits[r] = nidx;
                    }
                    cnt += __popcll(bal);
                }
            }
        }
    }

    __syncthreads();

    if (cnt > 64) {
        // rare overflow: exact ordered linear rescan (R4-verified loop)
        int c2 = 0;
        for (int basei = 0; basei < NSUP; basei += 64) {
            const int n = basei + lane;
            const float x = sx[n], y = sy[n], z = sz[n];
            const bool  m = read_mask(support_mask, b * NSUP + n, m4s);
            const float ss  = (x * x + y * y) + z * z;
            const float dot = __builtin_fmaf(qz, z,
                              __builtin_fmaf(qy, y, qx * x));
            const float d2  = (qq + ss) - 2.0f * dot;
            const bool within = (d2 <= 0.01f) && m;
            const unsigned long long bal = __ballot(within);
            if (within) {
                const int r = c2 + __popcll(bal & ((1ull << lane) - 1ull));
                if (r < NS) slots[r] = n;
            }
            c2 += __popcll(bal);
            if (c2 >= NS) break;
        }
        cnt = c2;
    } else {
        // bitonic sort, 64 lanes ascending (R6-verified); empties = INT_MAX
        int v = (lane < cnt) ? hits[lane] : 0x7FFFFFFF;
        #pragma unroll
        for (int k = 2; k <= 64; k <<= 1) {
            #pragma unroll
            for (int j = k >> 1; j > 0; j >>= 1) {
                const int pv = __shfl_xor(v, j, 64);
                const bool keep_min = ((lane & j) == 0) == ((lane & k) == 0);
                const int mn = min(v, pv), mx = max(v, pv);
                v = keep_min ? mn : mx;
            }
        }
        if (lane < NS && lane < cnt) slots[lane] = v;
    }
    const int found = (cnt < NS) ? cnt : NS;

    __syncthreads();
    const int first = (found > 0) ? slots[0] : 0;
    if (lane < NS && lane >= found) slots[lane] = first;
    __syncthreads();

    // padded idx -> ws (consumed by gather_feat)
    if (lane < NS) idx_ws[((size_t)b * NPOINT + p) * NS + lane] = slots[lane];

    // idx_mask (f32 0/1) after new_features
    const size_t nf_elems = (size_t)B * 67 * NPOINT * NS;
    if (lane < NS) {
        out[nf_elems + ((size_t)b * NPOINT + p) * NS + lane] =
            (lane < found) ? 1.0f : 0.0f;
    }

    // xyz channels (ch 0..2): 96 elements per query
    for (int i = 0; i < 2; ++i) {
        const int flat = i * 64 + lane;
        if (flat < 3 * NS) {
            const int ch = flat >> 5;
            const int k  = flat & 31;
            const int idx = slots[k];
            const float s = sx[(size_t)ch * NSUP + idx];
            const float q = (ch == 0) ? qx : ((ch == 1) ? qy : qz);
            out[(((size_t)b * 67 + ch) * NPOINT + p) * NS + k] = (s - q) / 0.1f;
        }
    }
}

// ---------- gather: one (b,ch) feature row in LDS, coalesced in/out ----------
__global__ __launch_bounds__(256) void gather_feat(
    const float* __restrict__ features, const int* __restrict__ idx_ws,
    float* __restrict__ out, int B)
{
    __shared__ float row[NSUP];                       // 32 KB
    const int bc = blockIdx.y;                        // b*NCH + ch
    const int b  = bc / NCH, ch = bc % NCH;
    const int p0 = blockIdx.x * QCHUNK;

    const float* src = features + ((size_t)b * NCH + ch) * NSUP;
    const float4* src4 = (const float4*)src;
    for (int i = threadIdx.x; i < NSUP / 4; i += 256)
        ((float4*)row)[i] = src4[i];
    __syncthreads();

    const int4* idx4 = (const int4*)(idx_ws + ((size_t)b * NPOINT + p0) * NS);
    float4* dst4 = (float4*)(out + (((size_t)b * 67 + 3 + ch) * NPOINT + p0) * NS);
    for (int e = threadIdx.x; e < QCHUNK * NS / 4; e += 256) {
        const int4 iv = idx4[e];
        dst4[e] = make_float4(row[iv.x], row[iv.y], row[iv.z], row[iv.w]);
    }
}

// ---------- proven R4 linear kernel (fallback if ws tiny) ----------
__global__ __launch_bounds__(256) void mqag_linear(
    const float* __restrict__ query_xyz, const float* __restrict__ support_xyz,
    const void* __restrict__ query_mask_raw, const void* __restrict__ support_mask_raw,
    const float* __restrict__ features, float* __restrict__ out, int B)
{
#pragma clang fp contract(off)
    const int wib  = threadIdx.x >> 6;
    const int lane = threadIdx.x & 63;
    const int qid  = blockIdx.x * 4 + wib;
    const int b    = qid / NPOINT;
    const int p    = qid % NPOINT;

    __shared__ int slots_all[4][NS];
    int* slots = slots_all[wib];

    const bool m4s = probe_mask4(support_mask_raw);
    const bool m4q = probe_mask4(query_mask_raw);

    const float* sx = support_xyz + (size_t)b * 3 * NSUP;
    const float* sy = sx + NSUP;
    const float* sz = sx + 2 * NSUP;

    const float qx = query_xyz[(size_t)b * 3 * NPOINT + p];
    const float qy = query_xyz[(size_t)b * 3 * NPOINT + NPOINT + p];
    const float qz = query_xyz[(size_t)b * 3 * NPOINT + 2 * NPOINT + p];
    const bool  qm = read_mask(query_mask_raw, b * NPOINT + p, m4q);
    const float qq = (qx * qx + qy * qy) + qz * qz;

    int cnt = 0;
    if (qm) {
        for (int base = 0; base < NSUP; base += 64) {
            const int n = base + lane;
            const float x = sx[n], y = sy[n], z = sz[n];
            const bool  m = read_mask(support_mask_raw, b * NSUP + n, m4s);
            const float ss  = (x * x + y * y) + z * z;
            const float dot = __builtin_fmaf(qz, z, __builtin_fmaf(qy, y, qx * x));
            const float d2  = (qq + ss) - 2.0f * dot;
            const bool within = (d2 <= 0.01f) && m;
            const unsigned long long bal = __ballot(within);
            if (within) {
                const int r = cnt + __popcll(bal & ((1ull << lane) - 1ull));
                if (r < NS) slots[r] = n;
            }
            cnt += __popcll(bal);
            if (cnt >= NS) break;
        }
    }
    const int found = cnt < NS ? cnt : NS;
    __syncthreads();
    const int first = (found > 0) ? slots[0] : 0;
    if (lane < NS && lane >= found) slots[lane] = first;
    __syncthreads();

    const size_t nf_elems = (size_t)B * 67 * NPOINT * NS;
    if (lane < NS) {
        out[nf_elems + ((size_t)b * NPOINT + p) * NS + lane] =
            (lane < found) ? 1.0f : 0.0f;
    }
    const float* feat = features + (size_t)b * NCH * NSUP;
    for (int i = 0; i < (67 * NS + 63) / 64; ++i) {
        const int flat = i * 64 + lane;
        if (flat < 67 * NS) {
            const int ch = flat >> 5;
            const int k  = flat & 31;
            const int idx = slots[k];
            float val;
            if (ch < 3) {
                const float s = sx[(size_t)ch * NSUP + idx];
                const float q = (ch == 0) ? qx : ((ch == 1) ? qy : qz);
                val = (s - q) / 0.1f;
            } else {
                val = feat[(size_t)(ch - 3) * NSUP + idx];
            }
            out[(((size_t)b * 67 + ch) * NPOINT + p) * NS + k] = val;
        }
    }
}

extern "C" void kernel_launch(void* const* d_in, const int* in_sizes, int n_in,
                              void* d_out, int out_size, void* d_ws, size_t ws_size,
                              hipStream_t stream) {
    const float* query_xyz    = (const float*)d_in[0];
    const float* support_xyz  = (const float*)d_in[1];
    const void*  query_mask   = d_in[2];
    const void*  support_mask = d_in[3];
    const float* features     = (const float*)d_in[4];

    const int B = in_sizes[0] / (3 * NPOINT);      // = 4

    // ws layout: pts | starts | cursors | idx
    const size_t off_pts     = 0;
    const size_t off_starts  = off_pts + (size_t)B * NSUP * sizeof(float4);
    const size_t off_cursors = off_starts + (size_t)B * (CELLS + 1) * sizeof(int);
    const size_t off_idx     = off_cursors + (size_t)B * CELLS * sizeof(int);
    const size_t need = off_idx + (size_t)B * NPOINT * NS * sizeof(int);

    if (ws_size >= need) {
        float4* pts  = (float4*)((char*)d_ws + off_pts);
        int* starts  = (int*)((char*)d_ws + off_starts);
        int* cursors = (int*)((char*)d_ws + off_cursors);
        int* idx_ws  = (int*)((char*)d_ws + off_idx);

        const int nzero = B * (CELLS + 1) + B * CELLS;   // starts+cursors contig
        hipLaunchKernelGGL(zero_ws, dim3((nzero + 255) / 256), dim3(256), 0,
                           stream, starts, nzero);
        hipLaunchKernelGGL(grid_hist, dim3(B * NSUP / 256), dim3(256), 0,
                           stream, support_xyz, support_mask, starts);
        hipLaunchKernelGGL(grid_scan, dim3(B), dim3(1024), 0, stream, starts);
        hipLaunchKernelGGL(grid_fill, dim3(B * NSUP / 256), dim3(256), 0,
                           stream, support_xyz, support_mask, starts, cursors, pts);
        hipLaunchKernelGGL(mqag_query, dim3(B * NPOINT / 4), dim3(256), 0,
                           stream, query_xyz, support_xyz, query_mask,
                           support_mask, pts, starts, idx_ws, (float*)d_out, B);
        hipLaunchKernelGGL(gather_feat, dim3(NPOINT / QCHUNK, B * NCH), dim3(256),
                           0, stream, features, idx_ws, (float*)d_out, B);
    } else {
        hipLaunchKernelGGL(mqag_linear, dim3(B * NPOINT / 4), dim3(256), 0,
                           stream, query_xyz, support_xyz, query_mask,
                           support_mask, features, (float*)d_out, B);
    }
}